// Round 13
// baseline (315.729 us; speedup 1.0000x reference)
//
#include <hip/hip_runtime.h>

// ---------------------------------------------------------------------------
// LP structure tables (verified rounds 3-12).
// ---------------------------------------------------------------------------
__device__ const signed char AZ_IDX[32][8] = {
    {4,5,6,7,8,9,0,0},{10,11,0,0,0,0,0,0},{4,5,6,7,8,9,10,11},
    {0,12,14,0,0,0,0,0},{2,12,14,0,0,0,0,0},{12,14,0,0,0,0,0,0},
    {1,13,15,0,0,0,0,0},{3,13,15,0,0,0,0,0},{13,15,0,0,0,0,0,0},
    {16,18,4,0,0,0,0,0},{16,18,6,0,0,0,0,0},{17,19,5,0,0,0,0,0},
    {17,19,7,0,0,0,0,0},{20,21,8,0,0,0,0,0},{20,21,10,0,0,0,0,0},
    {22,23,9,0,0,0,0,0},{22,23,11,0,0,0,0,0},
    {0},{0},{0},{0},{0},{0},{0},{0},{0},{0},{0},{0},{0},{0},{0}
};
__device__ const signed char AZ_SEL[32][8] = {
    {1,1,1,1,1,1,0,0},{1,1,0,0,0,0,0,0},{3,4,5,6,7,8,9,10},
    {1,11,13,0,0,0,0,0},{1,12,14,0,0,0,0,0},{1,1,0,0,0,0,0,0},
    {1,13,15,0,0,0,0,0},{1,14,16,0,0,0,0,0},{1,1,0,0,0,0,0,0},
    {17,19,2,0,0,0,0,0},{18,20,2,0,0,0,0,0},{19,21,2,0,0,0,0,0},
    {20,22,2,0,0,0,0,0},{23,25,2,0,0,0,0,0},{24,26,2,0,0,0,0,0},
    {27,29,2,0,0,0,0,0},{28,30,2,0,0,0,0,0},
    {0},{0},{0},{0},{0},{0},{0},{0},{0},{0},{0},{0},{0},{0},{0}
};
__device__ const signed char AT_IDX[32][3] = {
    {3,0,0},{6,0,0},{4,0,0},{7,0,0},
    {0,2,9},{0,2,11},{0,2,10},{0,2,12},{0,2,13},{0,2,15},{1,2,14},{1,2,16},
    {3,4,5},{6,7,8},{3,4,5},{6,7,8},
    {9,10,0},{11,12,0},{9,10,0},{11,12,0},
    {13,14,0},{13,14,0},{15,16,0},{15,16,0},
    {0},{0},{0},{0},{0},{0},{0},{0}
};
// Window bases for the 3 float4 mailbox reads (cover all M-row supports).
__device__ const signed char WBA[32] = {0,0,0,0, 4,4,4,4, 4,4,4,4, 0,0,0,0, 4,4,4,4, 8,8,8,8, 0,0,0,0,0,0,0,0};
__device__ const signed char WBB[32] = {12,12,12,12, 8,8,8,8, 8,8,8,8, 12,12,12,12, 16,16,16,16, 20,20,20,20, 0,0,0,0,0,0,0,0};
__device__ const signed char WBC[32] = {0,0,0,0, 16,16,16,16, 20,20,20,20, 0,0,0,0, 0,0,0,0, 0,0,0,0, 0,0,0,0,0,0,0,0};

#define LP_ITERS 400   // R10 FAILED at 300 (absmax 1616): 400 is a correctness constraint.

// Wave-cooperative GEMV row: 64 lanes split K, coalesced weight loads.
__device__ __forceinline__ float wave_dot(const float* __restrict__ wr,
                                          const float* __restrict__ h,
                                          int K, int lane) {
    float acc = 0.f;
    int j = lane;
    for (; j + 64 <= K; j += 64) acc = fmaf(h[j], wr[j], acc);
    if (j < K) acc = fmaf(h[j], wr[j], acc);
    acc += __shfl_xor(acc, 32, 64); acc += __shfl_xor(acc, 16, 64);
    acc += __shfl_xor(acc, 8, 64);  acc += __shfl_xor(acc, 4, 64);
    acc += __shfl_xor(acc, 2, 64);  acc += __shfl_xor(acc, 1, 64);
    return acc;
}

// ---------------------------------------------------------------------------
// Single fused kernel. 448 threads (7 waves).
// R13: dense/MLP layers as wave-cooperative row-GEMV — one wave-load touches
// 4 cache lines (256 contiguous bytes) instead of 64 (thread-per-output).
// ---------------------------------------------------------------------------
__global__ __launch_bounds__(448) void net_kernel(
    const float* __restrict__ xtraj, const float* __restrict__ x,
    const float* __restrict__ x_img,
    const float* __restrict__ cw1, const float* __restrict__ cb1,
    const float* __restrict__ cw2, const float* __restrict__ cb2,
    const float* __restrict__ w3, const float* __restrict__ b3,
    const float* __restrict__ w4, const float* __restrict__ b4,
    const float* __restrict__ pw1, const float* __restrict__ pb1,
    const float* __restrict__ pw2, const float* __restrict__ pb2,
    const float* __restrict__ pw3, const float* __restrict__ pb3,
    const float* __restrict__ vw1, const float* __restrict__ vb1,
    const float* __restrict__ vw2, const float* __restrict__ vb2,
    const float* __restrict__ vw3, const float* __restrict__ vb3,
    float* __restrict__ out)
{
    const int b = blockIdx.x;
    const int tid = threadIdx.x;
    const int wid = tid >> 6;       // wave 0..6
    const int lane = tid & 63;

    __shared__ __align__(16) float s_h1[4000];   // conv1 out; later LP scratch
    __shared__ __align__(16) float s_w2[5000];   // overlay: img[0:2500]; then cw2
    __shared__ __align__(16) float s_h2[320];
    __shared__ float s_hc[145];
    __shared__ float s_t1[152];
    __shared__ float s_m1[256];
    __shared__ float s_m2[256];

    float* Lb = s_h1;
    float* s_pr = Lb + 2285;
    float* s_vv = Lb + 2305;

    float* s_img = s_w2;          // 2500 (dead before conv2-weight reload)

    // ---- phase 0: stage image (float4) ----
    {
        const float4* src = (const float4*)(x_img + (size_t)b * 2500);
        float4* dst = (float4*)s_img;
        for (int i = tid; i < 625; i += 448) dst[i] = src[i];
    }
    __syncthreads();

    // ---- phase 1: conv1 (11x11, 50->40) + maxpool2 + relu, 1 quad/thread ----
    // Weights from global: wave-uniform addresses -> scalar loads.
    if (tid < 400) {
        const int py = tid / 20, px = tid % 20;
        const int C = 2 * px;
        float acc0[10], acc1[10], acc2[10], acc3[10];
        #pragma unroll
        for (int oc = 0; oc < 10; ++oc) { acc0[oc] = 0.f; acc1[oc] = 0.f; acc2[oc] = 0.f; acc3[oc] = 0.f; }
        for (int r = 0; r < 12; ++r) {
            float v[12];
            #pragma unroll
            for (int j = 0; j < 6; ++j) {
                float2 t = *(const float2*)&s_img[(2 * py + r) * 50 + C + 2 * j];
                v[2 * j] = t.x; v[2 * j + 1] = t.y;
            }
            if (r < 11) {
                #pragma unroll
                for (int oc = 0; oc < 10; ++oc) {
                    #pragma unroll
                    for (int kx = 0; kx < 11; ++kx) {
                        float w0 = cw1[oc * 121 + r * 11 + kx];
                        acc0[oc] = fmaf(v[kx], w0, acc0[oc]);
                        acc1[oc] = fmaf(v[kx + 1], w0, acc1[oc]);
                    }
                }
            }
            if (r >= 1) {
                #pragma unroll
                for (int oc = 0; oc < 10; ++oc) {
                    #pragma unroll
                    for (int kx = 0; kx < 11; ++kx) {
                        float w1 = cw1[oc * 121 + (r - 1) * 11 + kx];
                        acc2[oc] = fmaf(v[kx], w1, acc2[oc]);
                        acc3[oc] = fmaf(v[kx + 1], w1, acc3[oc]);
                    }
                }
            }
        }
        #pragma unroll
        for (int oc = 0; oc < 10; ++oc) {
            float m = fmaxf(fmaxf(acc0[oc], acc1[oc]), fmaxf(acc2[oc], acc3[oc]));
            s_h1[oc * 400 + tid] = fmaxf(m + cb1[oc], 0.f);
        }
    }
    __syncthreads();

    // ---- phase 2: reload s_w2 with conv2 weights ----
    {
        const float4* wsrc = (const float4*)cw2;
        float4* wdst = (float4*)s_w2;
        for (int i = tid; i < 1250; i += 448) wdst[i] = wsrc[i];
    }
    __syncthreads();

    // ---- conv2 (5x5, 20->16, 10ic->20oc) + maxpool4 + relu ----
    if (tid < 320) {
        const int oc = tid >> 4, cell = tid & 15;
        const int R0 = (cell >> 2) * 4, C0 = (cell & 3) * 4;
        float acc[16];
        #pragma unroll
        for (int i = 0; i < 16; ++i) acc[i] = 0.f;
        for (int ic = 0; ic < 10; ++ic) {
            const float* hb = &s_h1[ic * 400];
            const float* wb = &s_w2[oc * 250 + ic * 25];
            float v[8][8];
            #pragma unroll
            for (int r = 0; r < 8; ++r) {
                float4 t0 = *(const float4*)&hb[(R0 + r) * 20 + C0];
                float4 t1 = *(const float4*)&hb[(R0 + r) * 20 + C0 + 4];
                v[r][0] = t0.x; v[r][1] = t0.y; v[r][2] = t0.z; v[r][3] = t0.w;
                v[r][4] = t1.x; v[r][5] = t1.y; v[r][6] = t1.z; v[r][7] = t1.w;
            }
            #pragma unroll
            for (int k = 0; k < 5; ++k) {
                #pragma unroll
                for (int kx = 0; kx < 5; ++kx) {
                    float wv = wb[k * 5 + kx];
                    #pragma unroll
                    for (int o = 0; o < 4; ++o) {
                        #pragma unroll
                        for (int cc = 0; cc < 4; ++cc)
                            acc[o * 4 + cc] = fmaf(v[o + k][cc + kx], wv, acc[o * 4 + cc]);
                    }
                }
            }
        }
        float m = acc[0];
        #pragma unroll
        for (int i = 1; i < 16; ++i) m = fmaxf(m, acc[i]);
        s_h2[tid] = fmaxf(m + cb2[oc], 0.f);
    }
    __syncthreads();

    // ---- dense 320 -> 150, relu: wave-row GEMV ----
    for (int r = wid; r < 150; r += 7) {
        float d = wave_dot(w3 + r * 320, s_h2, 320, lane);
        if (lane == 0) s_t1[r] = fmaxf(d + b3[r], 0.f);
    }
    __syncthreads();

    // ---- dense 150 -> 100, relu -> s_hc[0:100]; xtraj concat ----
    if (tid < 45) s_hc[100 + tid] = xtraj[b * 45 + tid];
    for (int r = wid; r < 100; r += 7) {
        float d = wave_dot(w4 + r * 150, s_t1, 150, lane);
        if (lane == 0) s_hc[r] = fmaxf(d + b4[r], 0.f);
    }
    __syncthreads();

    // ---- MLP layer 1 (145 -> 100, both nets): 200 rows ----
    for (int r = wid; r < 200; r += 7) {
        const bool isv = r >= 100;
        const int o = isv ? r - 100 : r;
        const float* W = isv ? vw1 : pw1;
        const float* B = isv ? vb1 : pb1;
        float d = wave_dot(W + o * 145, s_hc, 145, lane);
        if (lane == 0) s_m1[(isv ? 128 : 0) + o] = fmaxf(d + B[o], 0.f);
    }
    __syncthreads();

    // ---- MLP layer 2 (100 -> 100, both nets): 200 rows ----
    for (int r = wid; r < 200; r += 7) {
        const bool isv = r >= 100;
        const int o = isv ? r - 100 : r;
        const float* W = isv ? vw2 : pw2;
        const float* B = isv ? vb2 : pb2;
        const float* h = isv ? (s_m1 + 128) : s_m1;
        float d = wave_dot(W + o * 100, h, 100, lane);
        if (lane == 0) s_m2[(isv ? 128 : 0) + o] = fmaxf(d + B[o], 0.f);
    }
    __syncthreads();

    // ---- MLP layer 3 (100 -> 20 p / 40 v): 60 rows + epilogue ----
    for (int r = wid; r < 60; r += 7) {
        const bool isv = r >= 20;
        const int o = isv ? r - 20 : r;
        const float* W = isv ? vw3 : pw3;
        const float* B = isv ? vb3 : pb3;
        const float* h = isv ? (s_m2 + 128) : s_m2;
        float d = wave_dot(W + o * 100, h, 100, lane);
        if (lane == 0) {
            float acc = d + B[o];
            if (isv) {
                s_vv[o] = acc;
                out[b * 100 + 60 + o] = 1000.f * (acc - x[b * 160 + 120 + o]);
            } else {
                s_pr[o] = acc;
                out[b * 100 + 40 + o] = 1000.f * (acc - x[b * 160 + o]);
            }
        }
    }
    __syncthreads();

    // =========================== LP phase ==================================
    if (tid >= 160) return;
    const int t = tid >> 5;
    const int l = tid & 31;
    const float* xt = xtraj + b * 45;
    const float* xb = x + b * 160;

    float* val = Lb + t * 32;
    float* Ag  = Lb + 160 + t * 408;
    float* bg  = Lb + 2200 + t * 17;

    // ---- value table ----
    {
        float v_ = 0.f;
        if (l == 1) v_ = 1.f;
        else if (l == 2) v_ = -1.f;
        else if (l >= 3 && l <= 10) {
            float r0 = xt[t], r1 = xt[5 + t];
            switch (l) {
                case 3:  v_ = r1 - s_pr[10 + t]; break;
                case 4:  v_ = r1 - s_pr[15 + t]; break;
                case 5:  v_ = s_pr[0 + t] - r0;  break;
                case 6:  v_ = s_pr[5 + t] - r0;  break;
                case 7:  v_ = r1 - xb[60 + 10 + t]; break;
                case 8:  v_ = r1 - xb[60 + 15 + t]; break;
                case 9:  v_ = xb[60 + 0 + t] - r0;  break;
                default: v_ = xb[60 + 5 + t] - r0;  break;
            }
        }
        else if (l >= 11 && l <= 16) v_ = -s_vv[5 * (l - 11) + t];
        else if (l >= 17 && l <= 22) v_ = xb[20 + 5 * (l - 17) + t];
        else if (l >= 23 && l <= 30) v_ = xb[80 + 5 * (l - 23) + t];
        val[l] = v_;
    }
    // ---- build dense A, b (intra-wave, DS in-order) ----
    for (int i = l; i < 408; i += 32) Ag[i] = 0.f;
    if (l < 17) {
        #pragma unroll
        for (int k = 0; k < 8; ++k) {
            int sel = AZ_SEL[l][k];
            if (sel != 0) Ag[l * 24 + (int)AZ_IDX[l][k]] = val[sel];
        }
        float bb = 0.f;
        if (l == 0) bb = xt[30 + t];
        else if (l == 1) bb = xt[35 + t];
        else if (l == 2) bb = xt[40 + t];
        else if (l == 5 || l == 8) bb = 1.f;
        bg[l] = bb;
    }

    // ---- numeric 12-slot window coefficients + c = (A^T b)_l ----
    const int bA = WBA[l], bB = WBB[l], bC = WBC[l];
    float cf[12];
    float cc = 0.f;
    #pragma unroll
    for (int k = 0; k < 12; ++k) cf[k] = 0.f;
    if (l < 24) {
        int e0 = AT_IDX[l][0], e1 = AT_IDX[l][1], e2 = AT_IDX[l][2];
        float a0 = Ag[e0 * 24 + l], a1 = Ag[e1 * 24 + l], a2 = Ag[e2 * 24 + l];
        cc = a0 * bg[e0] + a1 * bg[e1] + a2 * bg[e2];
        #pragma unroll
        for (int s = 0; s < 4; ++s)
            cf[s] = a0 * Ag[e0 * 24 + bA + s] + a1 * Ag[e1 * 24 + bA + s] + a2 * Ag[e2 * 24 + bA + s];
        #pragma unroll
        for (int s = 0; s < 4; ++s)
            cf[4 + s] = a0 * Ag[e0 * 24 + bB + s] + a1 * Ag[e1 * 24 + bB + s] + a2 * Ag[e2 * 24 + bB + s];
        if (l >= 4 && l < 12) {
            #pragma unroll
            for (int s = 0; s < 4; ++s)
                cf[8 + s] = a0 * Ag[e0 * 24 + bC + s] + a1 * Ag[e1 * 24 + bC + s] + a2 * Ag[e2 * 24 + bC + s];
        }
    }

    const bool isF  = (l >= 4 && l < 8);
    const bool isNN = (l >= 12);

    float* Zg = Lb + t * 32;   // mailbox (overlays dead val region)

    #define WDOT(vA, vB, vC)                                                    \
        (((cf[0]*vA.x + cf[1]*vA.y) + (cf[2]*vA.z + cf[3]*vA.w)) +              \
         ((cf[4]*vB.x + cf[5]*vB.y) + (cf[6]*vB.z + cf[7]*vB.w)) +              \
         ((cf[8]*vC.x + cf[9]*vC.y) + (cf[10]*vC.z + cf[11]*vC.w)))

    // ---- spectral norm: 25 M-applications, normalize every 5 ----
    float u = (l < 24) ? 1.f : 0.f;
    #pragma unroll 1
    for (int o = 0; o < 5; ++o) {
        #pragma unroll 1
        for (int ii = 0; ii < 5; ++ii) {
            Zg[l] = u;
            float4 vA = *(const float4*)(Zg + bA);
            float4 vB = *(const float4*)(Zg + bB);
            float4 vC = *(const float4*)(Zg + bC);
            u = WDOT(vA, vB, vC);
        }
        float s = u * u;
        s += __shfl_xor(s, 16, 32); s += __shfl_xor(s, 8, 32);
        s += __shfl_xor(s, 4, 32);  s += __shfl_xor(s, 2, 32);
        s += __shfl_xor(s, 1, 32);
        u = u / (sqrtf(s) + 1e-12f);
    }
    float tau;
    {
        Zg[l] = u;
        float4 vA = *(const float4*)(Zg + bA);
        float4 vB = *(const float4*)(Zg + bB);
        float4 vC = *(const float4*)(Zg + bC);
        float w = WDOT(vA, vB, vC);
        float s2 = u * w;   // u^T M u = ||A u||^2
        s2 += __shfl_xor(s2, 16, 32); s2 += __shfl_xor(s2, 8, 32);
        s2 += __shfl_xor(s2, 4, 32);  s2 += __shfl_xor(s2, 2, 32);
        s2 += __shfl_xor(s2, 1, 32);
        tau = 0.9f / (sqrtf(fmaxf(s2, 0.f)) + 1e-8f);
    }

    // ---- prescale by tau^2 ----
    const float t2 = tau * tau;
    #pragma unroll
    for (int k = 0; k < 12; ++k) cf[k] *= t2;
    const float cc2 = cc * t2;

    float zv = 0.f, zbv = 0.f, Q = 0.f;
    #pragma unroll 1
    for (int it = 0; it < LP_ITERS; ++it) {
        Zg[l] = zbv;                                  // ds_write_b32
        float4 vA = *(const float4*)(Zg + bA);        // 3x ds_read_b128
        float4 vB = *(const float4*)(Zg + bB);
        float4 vC = *(const float4*)(Zg + bC);
        float Qm = Q - cc2;                           // overlaps read wait
        float s = WDOT(vA, vB, vC);
        Q = Qm + s;

        float gg = zv - Q;
        float cl = fminf(fmaxf(gg, -tau), tau);       // med3 clamp
        float st = gg - cl;                           // soft-threshold
        float nn = fmaxf(gg, 0.f);
        float zn = isF ? st : (isNN ? nn : gg);
        zbv = fmaf(2.f, zn, -zv);
        zv = zn;
    }
    #undef WDOT

    // ---- write p (z0..z3) and f (z4..z7) ----
    {
        float* ob = out + b * 100;
        if (l < 4)      ob[l * 5 + t]            = 100.f * zv;
        else if (l < 8) ob[20 + (l - 4) * 5 + t] = 100.f * zv;
    }
}

extern "C" void kernel_launch(void* const* d_in, const int* in_sizes, int n_in,
                              void* d_out, int out_size, void* d_ws, size_t ws_size,
                              hipStream_t stream) {
    const float* xtraj = (const float*)d_in[0];
    const float* x     = (const float*)d_in[1];
    const float* x_img = (const float*)d_in[2];
    const float* cw1 = (const float*)d_in[3];
    const float* cb1 = (const float*)d_in[4];
    const float* cw2 = (const float*)d_in[5];
    const float* cb2 = (const float*)d_in[6];
    const float* w3  = (const float*)d_in[7];
    const float* b3  = (const float*)d_in[8];
    const float* w4  = (const float*)d_in[9];
    const float* b4  = (const float*)d_in[10];
    const float* pw1 = (const float*)d_in[11];
    const float* pb1 = (const float*)d_in[12];
    const float* pw2 = (const float*)d_in[13];
    const float* pb2 = (const float*)d_in[14];
    const float* pw3 = (const float*)d_in[15];
    const float* pb3 = (const float*)d_in[16];
    const float* vw1 = (const float*)d_in[17];
    const float* vb1 = (const float*)d_in[18];
    const float* vw2 = (const float*)d_in[19];
    const float* vb2 = (const float*)d_in[20];
    const float* vw3 = (const float*)d_in[21];
    const float* vb3 = (const float*)d_in[22];

    float* out = (float*)d_out;
    const int Bn = in_sizes[0] / 45;

    net_kernel<<<Bn, 448, 0, stream>>>(
        xtraj, x, x_img, cw1, cb1, cw2, cb2, w3, b3, w4, b4,
        pw1, pb1, pw2, pb2, pw3, pb3, vw1, vb1, vw2, vb2, vw3, vb3,
        out);
}

// Round 14
// 222.207 us; speedup vs baseline: 1.4209x; 1.4209x over previous
//
#include <hip/hip_runtime.h>

// ---------------------------------------------------------------------------
// LP structure tables (verified rounds 3-12).
// ---------------------------------------------------------------------------
__device__ const signed char AZ_IDX[32][8] = {
    {4,5,6,7,8,9,0,0},{10,11,0,0,0,0,0,0},{4,5,6,7,8,9,10,11},
    {0,12,14,0,0,0,0,0},{2,12,14,0,0,0,0,0},{12,14,0,0,0,0,0,0},
    {1,13,15,0,0,0,0,0},{3,13,15,0,0,0,0,0},{13,15,0,0,0,0,0,0},
    {16,18,4,0,0,0,0,0},{16,18,6,0,0,0,0,0},{17,19,5,0,0,0,0,0},
    {17,19,7,0,0,0,0,0},{20,21,8,0,0,0,0,0},{20,21,10,0,0,0,0,0},
    {22,23,9,0,0,0,0,0},{22,23,11,0,0,0,0,0},
    {0},{0},{0},{0},{0},{0},{0},{0},{0},{0},{0},{0},{0},{0},{0}
};
__device__ const signed char AZ_SEL[32][8] = {
    {1,1,1,1,1,1,0,0},{1,1,0,0,0,0,0,0},{3,4,5,6,7,8,9,10},
    {1,11,13,0,0,0,0,0},{1,12,14,0,0,0,0,0},{1,1,0,0,0,0,0,0},
    {1,13,15,0,0,0,0,0},{1,14,16,0,0,0,0,0},{1,1,0,0,0,0,0,0},
    {17,19,2,0,0,0,0,0},{18,20,2,0,0,0,0,0},{19,21,2,0,0,0,0,0},
    {20,22,2,0,0,0,0,0},{23,25,2,0,0,0,0,0},{24,26,2,0,0,0,0,0},
    {27,29,2,0,0,0,0,0},{28,30,2,0,0,0,0,0},
    {0},{0},{0},{0},{0},{0},{0},{0},{0},{0},{0},{0},{0},{0},{0}
};
__device__ const signed char AT_IDX[32][3] = {
    {3,0,0},{6,0,0},{4,0,0},{7,0,0},
    {0,2,9},{0,2,11},{0,2,10},{0,2,12},{0,2,13},{0,2,15},{1,2,14},{1,2,16},
    {3,4,5},{6,7,8},{3,4,5},{6,7,8},
    {9,10,0},{11,12,0},{9,10,0},{11,12,0},
    {13,14,0},{13,14,0},{15,16,0},{15,16,0},
    {0},{0},{0},{0},{0},{0},{0},{0}
};
// Window bases for the 3 float4 mailbox reads (cover all M-row supports).
__device__ const signed char WBA[32] = {0,0,0,0, 4,4,4,4, 4,4,4,4, 0,0,0,0, 4,4,4,4, 8,8,8,8, 0,0,0,0,0,0,0,0};
__device__ const signed char WBB[32] = {12,12,12,12, 8,8,8,8, 8,8,8,8, 12,12,12,12, 16,16,16,16, 20,20,20,20, 0,0,0,0,0,0,0,0};
__device__ const signed char WBC[32] = {0,0,0,0, 16,16,16,16, 20,20,20,20, 0,0,0,0, 0,0,0,0, 0,0,0,0, 0,0,0,0,0,0,0,0};

#define LP_ITERS 400   // R10 FAILED at 300 (absmax 1616): 400 is a correctness constraint.

// ---------------------------------------------------------------------------
// Single fused kernel. 448 threads (7 waves). R14 = exact revert to R12
// (best verified config: thread-per-output dense with 2-way k-split).
// R13's wave-cooperative GEMV regressed 142->257 us (shuffle-reduce latency
// dominates) — do not reintroduce.
// ---------------------------------------------------------------------------
__global__ __launch_bounds__(448) void net_kernel(
    const float* __restrict__ xtraj, const float* __restrict__ x,
    const float* __restrict__ x_img,
    const float* __restrict__ cw1, const float* __restrict__ cb1,
    const float* __restrict__ cw2, const float* __restrict__ cb2,
    const float* __restrict__ w3, const float* __restrict__ b3,
    const float* __restrict__ w4, const float* __restrict__ b4,
    const float* __restrict__ pw1, const float* __restrict__ pb1,
    const float* __restrict__ pw2, const float* __restrict__ pb2,
    const float* __restrict__ pw3, const float* __restrict__ pb3,
    const float* __restrict__ vw1, const float* __restrict__ vb1,
    const float* __restrict__ vw2, const float* __restrict__ vb2,
    const float* __restrict__ vw3, const float* __restrict__ vb3,
    float* __restrict__ out)
{
    const int b = blockIdx.x;
    const int tid = threadIdx.x;

    __shared__ __align__(16) float s_h1[4000];   // conv1 out; later scratch + LP
    __shared__ __align__(16) float s_w2[5000];   // overlay: img[0:2500]; then cw2
    __shared__ __align__(16) float s_h2[320];
    __shared__ float s_hc[145];
    __shared__ float s_t1[152];
    __shared__ float s_m1[256];
    __shared__ float s_m2[256];

    float* Lb = s_h1;
    float* s_pr = Lb + 2285;
    float* s_vv = Lb + 2305;
    float* S    = Lb + 3000;      // dense partial-sum scratch (dead h1 region)

    float* s_img = s_w2;          // 2500 (dead before conv2-weight reload)

    // ---- phase 0: stage image (float4) ----
    {
        const float4* src = (const float4*)(x_img + (size_t)b * 2500);
        float4* dst = (float4*)s_img;
        for (int i = tid; i < 625; i += 448) dst[i] = src[i];
    }
    __syncthreads();

    // ---- phase 1: conv1 (11x11, 50->40) + maxpool2 + relu, 1 quad/thread ----
    // Weights from global: wave-uniform addresses -> scalar loads.
    if (tid < 400) {
        const int py = tid / 20, px = tid % 20;
        const int C = 2 * px;
        float acc0[10], acc1[10], acc2[10], acc3[10];
        #pragma unroll
        for (int oc = 0; oc < 10; ++oc) { acc0[oc] = 0.f; acc1[oc] = 0.f; acc2[oc] = 0.f; acc3[oc] = 0.f; }
        for (int r = 0; r < 12; ++r) {
            float v[12];
            #pragma unroll
            for (int j = 0; j < 6; ++j) {
                float2 t = *(const float2*)&s_img[(2 * py + r) * 50 + C + 2 * j];
                v[2 * j] = t.x; v[2 * j + 1] = t.y;
            }
            if (r < 11) {
                #pragma unroll
                for (int oc = 0; oc < 10; ++oc) {
                    #pragma unroll
                    for (int kx = 0; kx < 11; ++kx) {
                        float w0 = cw1[oc * 121 + r * 11 + kx];
                        acc0[oc] = fmaf(v[kx], w0, acc0[oc]);
                        acc1[oc] = fmaf(v[kx + 1], w0, acc1[oc]);
                    }
                }
            }
            if (r >= 1) {
                #pragma unroll
                for (int oc = 0; oc < 10; ++oc) {
                    #pragma unroll
                    for (int kx = 0; kx < 11; ++kx) {
                        float w1 = cw1[oc * 121 + (r - 1) * 11 + kx];
                        acc2[oc] = fmaf(v[kx], w1, acc2[oc]);
                        acc3[oc] = fmaf(v[kx + 1], w1, acc3[oc]);
                    }
                }
            }
        }
        #pragma unroll
        for (int oc = 0; oc < 10; ++oc) {
            float m = fmaxf(fmaxf(acc0[oc], acc1[oc]), fmaxf(acc2[oc], acc3[oc]));
            s_h1[oc * 400 + tid] = fmaxf(m + cb1[oc], 0.f);
        }
    }
    __syncthreads();

    // ---- phase 2: reload s_w2 with conv2 weights ----
    {
        const float4* wsrc = (const float4*)cw2;
        float4* wdst = (float4*)s_w2;
        for (int i = tid; i < 1250; i += 448) wdst[i] = wsrc[i];
    }
    __syncthreads();

    // ---- conv2 (5x5, 20->16, 10ic->20oc) + maxpool4 + relu ----
    if (tid < 320) {
        const int oc = tid >> 4, cell = tid & 15;
        const int R0 = (cell >> 2) * 4, C0 = (cell & 3) * 4;
        float acc[16];
        #pragma unroll
        for (int i = 0; i < 16; ++i) acc[i] = 0.f;
        for (int ic = 0; ic < 10; ++ic) {
            const float* hb = &s_h1[ic * 400];
            const float* wb = &s_w2[oc * 250 + ic * 25];
            float v[8][8];
            #pragma unroll
            for (int r = 0; r < 8; ++r) {
                float4 t0 = *(const float4*)&hb[(R0 + r) * 20 + C0];
                float4 t1 = *(const float4*)&hb[(R0 + r) * 20 + C0 + 4];
                v[r][0] = t0.x; v[r][1] = t0.y; v[r][2] = t0.z; v[r][3] = t0.w;
                v[r][4] = t1.x; v[r][5] = t1.y; v[r][6] = t1.z; v[r][7] = t1.w;
            }
            #pragma unroll
            for (int k = 0; k < 5; ++k) {
                #pragma unroll
                for (int kx = 0; kx < 5; ++kx) {
                    float wv = wb[k * 5 + kx];
                    #pragma unroll
                    for (int o = 0; o < 4; ++o) {
                        #pragma unroll
                        for (int cc = 0; cc < 4; ++cc)
                            acc[o * 4 + cc] = fmaf(v[o + k][cc + kx], wv, acc[o * 4 + cc]);
                    }
                }
            }
        }
        float m = acc[0];
        #pragma unroll
        for (int i = 1; i < 16; ++i) m = fmaxf(m, acc[i]);
        s_h2[tid] = fmaxf(m + cb2[oc], 0.f);
    }
    __syncthreads();

    // ---- dense 320 -> 150, relu (2 threads/output, 160 terms each) ----
    if (tid < 300) {
        const int half = tid / 150, o = tid % 150;
        const float* w = w3 + o * 320 + half * 160;
        const float* h = s_h2 + half * 160;
        float a0 = 0.f, a1 = 0.f, a2 = 0.f, a3 = 0.f;
        for (int k = 0; k < 160; k += 4) {
            a0 = fmaf(h[k],     w[k],     a0);
            a1 = fmaf(h[k + 1], w[k + 1], a1);
            a2 = fmaf(h[k + 2], w[k + 2], a2);
            a3 = fmaf(h[k + 3], w[k + 3], a3);
        }
        S[tid] = (a0 + a1) + (a2 + a3);
    }
    __syncthreads();
    if (tid < 150) s_t1[tid] = fmaxf(S[tid] + S[tid + 150] + b3[tid], 0.f);
    __syncthreads();

    // ---- dense 150 -> 100, relu (2 threads/output, 75 terms) + xtraj concat ----
    if (tid < 200) {
        const int half = tid / 100, o = tid % 100;
        const float* w = w4 + o * 150 + half * 75;
        const float* h = s_t1 + half * 75;
        float a0 = 0.f;
        for (int k = 0; k < 75; ++k) a0 = fmaf(h[k], w[k], a0);
        S[tid] = a0;
    } else if (tid >= 200 && tid < 245) {
        s_hc[100 + (tid - 200)] = xtraj[b * 45 + (tid - 200)];
    }
    __syncthreads();
    if (tid < 100) s_hc[tid] = fmaxf(S[tid] + S[tid + 100] + b4[tid], 0.f);
    __syncthreads();

    // ---- MLP layer 1 (145 -> 100, both nets; 2 threads/output) ----
    if (tid < 200) {
        const int half = tid / 100, o = tid % 100;
        const int k0 = half ? 73 : 0, kn = half ? 72 : 73;
        const float* w = pw1 + o * 145 + k0;
        const float* h = s_hc + k0;
        float a0 = 0.f;
        for (int k = 0; k < kn; ++k) a0 = fmaf(h[k], w[k], a0);
        S[tid] = a0;
    } else if (tid < 400) {
        const int i = tid - 200;
        const int half = i / 100, o = i % 100;
        const int k0 = half ? 73 : 0, kn = half ? 72 : 73;
        const float* w = vw1 + o * 145 + k0;
        const float* h = s_hc + k0;
        float a0 = 0.f;
        for (int k = 0; k < kn; ++k) a0 = fmaf(h[k], w[k], a0);
        S[tid] = a0;
    }
    __syncthreads();
    if (tid < 100) s_m1[tid] = fmaxf(S[tid] + S[tid + 100] + pb1[tid], 0.f);
    else if (tid >= 128 && tid < 228) {
        const int i = tid - 128;
        s_m1[tid] = fmaxf(S[200 + i] + S[300 + i] + vb1[i], 0.f);
    }
    __syncthreads();

    // ---- MLP layer 2 (100 -> 100, both nets; 2 threads/output) ----
    if (tid < 200) {
        const int half = tid / 100, o = tid % 100;
        const float* w = pw2 + o * 100 + half * 50;
        const float* h = s_m1 + half * 50;
        float a0 = 0.f;
        for (int k = 0; k < 50; ++k) a0 = fmaf(h[k], w[k], a0);
        S[tid] = a0;
    } else if (tid < 400) {
        const int i = tid - 200;
        const int half = i / 100, o = i % 100;
        const float* w = vw2 + o * 100 + half * 50;
        const float* h = s_m1 + 128 + half * 50;
        float a0 = 0.f;
        for (int k = 0; k < 50; ++k) a0 = fmaf(h[k], w[k], a0);
        S[tid] = a0;
    }
    __syncthreads();
    if (tid < 100) s_m2[tid] = fmaxf(S[tid] + S[tid + 100] + pb2[tid], 0.f);
    else if (tid >= 128 && tid < 228) {
        const int i = tid - 128;
        s_m2[tid] = fmaxf(S[200 + i] + S[300 + i] + vb2[i], 0.f);
    }
    __syncthreads();

    // ---- MLP layer 3 (100 -> 20 / 40; 2 threads/output) ----
    if (tid < 40) {
        const int half = tid / 20, o = tid % 20;
        const float* w = pw3 + o * 100 + half * 50;
        const float* h = s_m2 + half * 50;
        float a0 = 0.f;
        for (int k = 0; k < 50; ++k) a0 = fmaf(h[k], w[k], a0);
        S[tid] = a0;
    } else if (tid >= 128 && tid < 208) {
        const int i = tid - 128;
        const int half = i / 40, o = i % 40;
        const float* w = vw3 + o * 100 + half * 50;
        const float* h = s_m2 + 128 + half * 50;
        float a0 = 0.f;
        for (int k = 0; k < 50; ++k) a0 = fmaf(h[k], w[k], a0);
        S[64 + i] = a0;
    }
    __syncthreads();
    if (tid < 20) {
        float acc = S[tid] + S[tid + 20] + pb3[tid];
        s_pr[tid] = acc;
        out[b * 100 + 40 + tid] = 1000.f * (acc - x[b * 160 + tid]);
    } else if (tid >= 128 && tid < 168) {
        const int i = tid - 128;
        float acc = S[64 + i] + S[64 + i + 40] + vb3[i];
        s_vv[i] = acc;
        out[b * 100 + 60 + i] = 1000.f * (acc - x[b * 160 + 120 + i]);
    }
    __syncthreads();

    // =========================== LP phase ==================================
    if (tid >= 160) return;
    const int t = tid >> 5;
    const int l = tid & 31;
    const float* xt = xtraj + b * 45;
    const float* xb = x + b * 160;

    float* val = Lb + t * 32;
    float* Ag  = Lb + 160 + t * 408;
    float* bg  = Lb + 2200 + t * 17;

    // ---- value table ----
    {
        float v_ = 0.f;
        if (l == 1) v_ = 1.f;
        else if (l == 2) v_ = -1.f;
        else if (l >= 3 && l <= 10) {
            float r0 = xt[t], r1 = xt[5 + t];
            switch (l) {
                case 3:  v_ = r1 - s_pr[10 + t]; break;
                case 4:  v_ = r1 - s_pr[15 + t]; break;
                case 5:  v_ = s_pr[0 + t] - r0;  break;
                case 6:  v_ = s_pr[5 + t] - r0;  break;
                case 7:  v_ = r1 - xb[60 + 10 + t]; break;
                case 8:  v_ = r1 - xb[60 + 15 + t]; break;
                case 9:  v_ = xb[60 + 0 + t] - r0;  break;
                default: v_ = xb[60 + 5 + t] - r0;  break;
            }
        }
        else if (l >= 11 && l <= 16) v_ = -s_vv[5 * (l - 11) + t];
        else if (l >= 17 && l <= 22) v_ = xb[20 + 5 * (l - 17) + t];
        else if (l >= 23 && l <= 30) v_ = xb[80 + 5 * (l - 23) + t];
        val[l] = v_;
    }
    // ---- build dense A, b (intra-wave, DS in-order) ----
    for (int i = l; i < 408; i += 32) Ag[i] = 0.f;
    if (l < 17) {
        #pragma unroll
        for (int k = 0; k < 8; ++k) {
            int sel = AZ_SEL[l][k];
            if (sel != 0) Ag[l * 24 + (int)AZ_IDX[l][k]] = val[sel];
        }
        float bb = 0.f;
        if (l == 0) bb = xt[30 + t];
        else if (l == 1) bb = xt[35 + t];
        else if (l == 2) bb = xt[40 + t];
        else if (l == 5 || l == 8) bb = 1.f;
        bg[l] = bb;
    }

    // ---- numeric 12-slot window coefficients + c = (A^T b)_l ----
    const int bA = WBA[l], bB = WBB[l], bC = WBC[l];
    float cf[12];
    float cc = 0.f;
    #pragma unroll
    for (int k = 0; k < 12; ++k) cf[k] = 0.f;
    if (l < 24) {
        int e0 = AT_IDX[l][0], e1 = AT_IDX[l][1], e2 = AT_IDX[l][2];
        float a0 = Ag[e0 * 24 + l], a1 = Ag[e1 * 24 + l], a2 = Ag[e2 * 24 + l];
        cc = a0 * bg[e0] + a1 * bg[e1] + a2 * bg[e2];
        #pragma unroll
        for (int s = 0; s < 4; ++s)
            cf[s] = a0 * Ag[e0 * 24 + bA + s] + a1 * Ag[e1 * 24 + bA + s] + a2 * Ag[e2 * 24 + bA + s];
        #pragma unroll
        for (int s = 0; s < 4; ++s)
            cf[4 + s] = a0 * Ag[e0 * 24 + bB + s] + a1 * Ag[e1 * 24 + bB + s] + a2 * Ag[e2 * 24 + bB + s];
        if (l >= 4 && l < 12) {
            #pragma unroll
            for (int s = 0; s < 4; ++s)
                cf[8 + s] = a0 * Ag[e0 * 24 + bC + s] + a1 * Ag[e1 * 24 + bC + s] + a2 * Ag[e2 * 24 + bC + s];
        }
    }

    const bool isF  = (l >= 4 && l < 8);
    const bool isNN = (l >= 12);

    float* Zg = Lb + t * 32;   // mailbox (overlays dead val region)

    #define WDOT(vA, vB, vC)                                                    \
        (((cf[0]*vA.x + cf[1]*vA.y) + (cf[2]*vA.z + cf[3]*vA.w)) +              \
         ((cf[4]*vB.x + cf[5]*vB.y) + (cf[6]*vB.z + cf[7]*vB.w)) +              \
         ((cf[8]*vC.x + cf[9]*vC.y) + (cf[10]*vC.z + cf[11]*vC.w)))

    // ---- spectral norm: 25 M-applications, normalize every 5 ----
    float u = (l < 24) ? 1.f : 0.f;
    #pragma unroll 1
    for (int o = 0; o < 5; ++o) {
        #pragma unroll 1
        for (int ii = 0; ii < 5; ++ii) {
            Zg[l] = u;
            float4 vA = *(const float4*)(Zg + bA);
            float4 vB = *(const float4*)(Zg + bB);
            float4 vC = *(const float4*)(Zg + bC);
            u = WDOT(vA, vB, vC);
        }
        float s = u * u;
        s += __shfl_xor(s, 16, 32); s += __shfl_xor(s, 8, 32);
        s += __shfl_xor(s, 4, 32);  s += __shfl_xor(s, 2, 32);
        s += __shfl_xor(s, 1, 32);
        u = u / (sqrtf(s) + 1e-12f);
    }
    float tau;
    {
        Zg[l] = u;
        float4 vA = *(const float4*)(Zg + bA);
        float4 vB = *(const float4*)(Zg + bB);
        float4 vC = *(const float4*)(Zg + bC);
        float w = WDOT(vA, vB, vC);
        float s2 = u * w;   // u^T M u = ||A u||^2
        s2 += __shfl_xor(s2, 16, 32); s2 += __shfl_xor(s2, 8, 32);
        s2 += __shfl_xor(s2, 4, 32);  s2 += __shfl_xor(s2, 2, 32);
        s2 += __shfl_xor(s2, 1, 32);
        tau = 0.9f / (sqrtf(fmaxf(s2, 0.f)) + 1e-8f);
    }

    // ---- prescale by tau^2 ----
    const float t2 = tau * tau;
    #pragma unroll
    for (int k = 0; k < 12; ++k) cf[k] *= t2;
    const float cc2 = cc * t2;

    float zv = 0.f, zbv = 0.f, Q = 0.f;
    #pragma unroll 1
    for (int it = 0; it < LP_ITERS; ++it) {
        Zg[l] = zbv;                                  // ds_write_b32
        float4 vA = *(const float4*)(Zg + bA);        // 3x ds_read_b128
        float4 vB = *(const float4*)(Zg + bB);
        float4 vC = *(const float4*)(Zg + bC);
        float Qm = Q - cc2;                           // overlaps read wait
        float s = WDOT(vA, vB, vC);
        Q = Qm + s;

        float gg = zv - Q;
        float cl = fminf(fmaxf(gg, -tau), tau);       // med3 clamp
        float st = gg - cl;                           // soft-threshold
        float nn = fmaxf(gg, 0.f);
        float zn = isF ? st : (isNN ? nn : gg);
        zbv = fmaf(2.f, zn, -zv);
        zv = zn;
    }
    #undef WDOT

    // ---- write p (z0..z3) and f (z4..z7) ----
    {
        float* ob = out + b * 100;
        if (l < 4)      ob[l * 5 + t]            = 100.f * zv;
        else if (l < 8) ob[20 + (l - 4) * 5 + t] = 100.f * zv;
    }
}

extern "C" void kernel_launch(void* const* d_in, const int* in_sizes, int n_in,
                              void* d_out, int out_size, void* d_ws, size_t ws_size,
                              hipStream_t stream) {
    const float* xtraj = (const float*)d_in[0];
    const float* x     = (const float*)d_in[1];
    const float* x_img = (const float*)d_in[2];
    const float* cw1 = (const float*)d_in[3];
    const float* cb1 = (const float*)d_in[4];
    const float* cw2 = (const float*)d_in[5];
    const float* cb2 = (const float*)d_in[6];
    const float* w3  = (const float*)d_in[7];
    const float* b3  = (const float*)d_in[8];
    const float* w4  = (const float*)d_in[9];
    const float* b4  = (const float*)d_in[10];
    const float* pw1 = (const float*)d_in[11];
    const float* pb1 = (const float*)d_in[12];
    const float* pw2 = (const float*)d_in[13];
    const float* pb2 = (const float*)d_in[14];
    const float* pw3 = (const float*)d_in[15];
    const float* pb3 = (const float*)d_in[16];
    const float* vw1 = (const float*)d_in[17];
    const float* vb1 = (const float*)d_in[18];
    const float* vw2 = (const float*)d_in[19];
    const float* vb2 = (const float*)d_in[20];
    const float* vw3 = (const float*)d_in[21];
    const float* vb3 = (const float*)d_in[22];

    float* out = (float*)d_out;
    const int Bn = in_sizes[0] / 45;

    net_kernel<<<Bn, 448, 0, stream>>>(
        xtraj, x, x_img, cw1, cb1, cw2, cb2, w3, b3, w4, b4,
        pw1, pb1, pw2, pb2, pw3, pb3, vw1, vb1, vw2, vb2, vw3, vb3,
        out);
}